// Round 12
// baseline (202.206 us; speedup 1.0000x reference)
//
#include <hip/hip_runtime.h>
#include <hip/hip_bf16.h>
#include <stdint.h>

// Problem constants: B=2, S=2048, D=1024, H=16, DH=64, M = B*S = 4096.

typedef __attribute__((ext_vector_type(8))) short bf16x8;
typedef __attribute__((ext_vector_type(4))) float f32x4;

__device__ __forceinline__ void gld16(const void* g, void* l) {
  __builtin_amdgcn_global_load_lds((const __attribute__((address_space(1))) void*)g,
                                   (__attribute__((address_space(3))) void*)l, 16, 0, 0);
}

__device__ __forceinline__ unsigned short f2b(float f) {
  __hip_bfloat16 h = __float2bfloat16(f);
  return *reinterpret_cast<unsigned short*>(&h);
}

// ---------------- prep: x fp32->bf16 (blocks 0..4095) + W transpose (4096..5119) ----------------
__global__ __launch_bounds__(256) void prep_kernel(const float* __restrict__ x,
                                                   const float* __restrict__ Wq,
                                                   const float* __restrict__ Wk,
                                                   const float* __restrict__ Wv,
                                                   const float* __restrict__ Wo,
                                                   unsigned short* __restrict__ xb,
                                                   unsigned short* __restrict__ wt) {
  __shared__ unsigned short Ls[64 * 72];
  int bid = blockIdx.x;
  int t = threadIdx.x;
  if (bid < 4096) {
    int i = (bid * 256 + t) * 4;
    float4 v = *(const float4*)(x + i);
    ushort4 o = make_ushort4(f2b(v.x), f2b(v.y), f2b(v.z), f2b(v.w));
    *(ushort4*)(xb + i) = o;
    return;
  }
  int tid = bid - 4096;
  int z = tid >> 8, rem = tid & 255;
  int bx = rem & 15, by = rem >> 4;
  const float* src = (z == 0) ? Wq : (z == 1) ? Wk : (z == 2) ? Wv : Wo;
  unsigned short* dst = wt + (size_t)z * 1024 * 1024;
  int k0 = bx * 64, n0 = by * 64;
  int c4 = t & 15;
#pragma unroll
  for (int it = 0; it < 4; ++it) {
    int row = it * 16 + (t >> 4);
    float4 v = *(const float4*)(src + (k0 + row) * 1024 + n0 + c4 * 4);
    Ls[(c4 * 4 + 0) * 72 + row] = f2b(v.x);
    Ls[(c4 * 4 + 1) * 72 + row] = f2b(v.y);
    Ls[(c4 * 4 + 2) * 72 + row] = f2b(v.z);
    Ls[(c4 * 4 + 3) * 72 + row] = f2b(v.w);
  }
  __syncthreads();
  int nr = t >> 2, kc = (t & 3) * 16;
  *(uint4*)(dst + (size_t)(n0 + nr) * 1024 + k0 + kc) = *(uint4*)&Ls[nr * 72 + kc];
  *(uint4*)(dst + (size_t)(n0 + nr) * 1024 + k0 + kc + 8) = *(uint4*)&Ls[nr * 72 + kc + 8];
}

// ---------------- fused QKV GEMM (round-1 BK=32 structure — measured local optimum) ----------------
// BK=64 regressed (r7); explicit dbuf regressed (r2). Keep BK=32, 2-barrier loop.
// Q is pre-scaled by 0.125*log2(e) so attention can use raw exp2.
__global__ __launch_bounds__(256) void gemm_qkv(const unsigned short* __restrict__ Ab,
                                                const unsigned short* __restrict__ Bt,
                                                const float* __restrict__ bq,
                                                const float* __restrict__ bk,
                                                const float* __restrict__ bv,
                                                unsigned short* __restrict__ qb,
                                                unsigned short* __restrict__ kb,
                                                unsigned short* __restrict__ vtb) {
  __shared__ unsigned short As[128 * 32];
  __shared__ unsigned short Bs[128 * 32];
  __shared__ unsigned short Es[128 * 72];  // also viewed as [64][136] for V (9216 >= 8704)
  const int t = threadIdx.x;
  const int lane = t & 63, wave = t >> 6;
  const int m0 = blockIdx.x * 128, n0 = blockIdx.y * 128;
  const int wr = (wave >> 1) * 64, wc = (wave & 1) * 64;
  const int fr = lane & 15, fq = lane >> 4;
  f32x4 acc[4][4] = {};
  for (int kt = 0; kt < 32; ++kt) {
    const unsigned short* Ag = Ab + (size_t)m0 * 1024 + kt * 32;
    const unsigned short* Bg = Bt + (size_t)n0 * 1024 + kt * 32;
#pragma unroll
    for (int rep = 0; rep < 2; ++rep) {
      int c = t + rep * 256;
      int row = c >> 2, col = (c & 3) * 8;
      gld16(Ag + (size_t)row * 1024 + col, (void*)(As + c * 8));
      gld16(Bg + (size_t)row * 1024 + col, (void*)(Bs + c * 8));
    }
    __syncthreads();
    bf16x8 a[4], b[4];
#pragma unroll
    for (int i = 0; i < 4; ++i) a[i] = *(const bf16x8*)&As[(wr + i * 16 + fr) * 32 + fq * 8];
#pragma unroll
    for (int j = 0; j < 4; ++j) b[j] = *(const bf16x8*)&Bs[(wc + j * 16 + fr) * 32 + fq * 8];
#pragma unroll
    for (int i = 0; i < 4; ++i)
#pragma unroll
      for (int j = 0; j < 4; ++j)
        acc[i][j] = __builtin_amdgcn_mfma_f32_16x16x32_bf16(a[i], b[j], acc[i][j], 0, 0, 0);
    __syncthreads();
  }
  const int which = n0 >> 10;  // 0=q, 1=k, 2=v (uniform per block)
  const int bidx = m0 >> 11, s0 = m0 & 2047;
  if (which == 2) {
    // V: Es as [dh_l][136] (s-contig rows), b64 LDS writes, 256-B coalesced global rows.
#pragma unroll
    for (int nh = 0; nh < 2; ++nh) {
      if ((wc >> 6) == nh) {
#pragma unroll
        for (int j = 0; j < 4; ++j) {
          int col = j * 16 + fr;  // dh_l 0..63
          float bias = bv[(n0 + nh * 64 + col) & 1023];
#pragma unroll
          for (int i = 0; i < 4; ++i) {
            int sl = wr + i * 16 + fq * 4;
            ushort4 pk;
            pk.x = f2b(acc[i][j][0] + bias);
            pk.y = f2b(acc[i][j][1] + bias);
            pk.z = f2b(acc[i][j][2] + bias);
            pk.w = f2b(acc[i][j][3] + bias);
            *(uint2*)&Es[col * 136 + sl] = *(uint2*)&pk;
          }
        }
      }
      __syncthreads();
      int h = ((n0 + nh * 64) & 1023) >> 6;
#pragma unroll
      for (int it = 0; it < 4; ++it) {
        int dh = it * 16 + (t >> 4);
        int ck = (t & 15) * 8;
        uint4 vv = *(uint4*)&Es[dh * 136 + ck];
        *(uint4*)&vtb[(size_t)((bidx * 16 + h) * 64 + dh) * 2048 + s0 + ck] = vv;
      }
      __syncthreads();
    }
  } else {
    unsigned short* dst = (which == 0) ? qb : kb;
    const float* bias_p = (which == 0) ? bq : bk;
    float scale = (which == 0) ? 0.1803368801111204f : 1.0f;
#pragma unroll
    for (int nh = 0; nh < 2; ++nh) {
      if ((wc >> 6) == nh) {
#pragma unroll
        for (int j = 0; j < 4; ++j) {
          int col = j * 16 + fr;
          float bias = bias_p[(n0 + nh * 64 + col) & 1023];
#pragma unroll
          for (int i = 0; i < 4; ++i)
#pragma unroll
            for (int r = 0; r < 4; ++r) {
              int sl = wr + i * 16 + fq * 4 + r;
              Es[sl * 72 + col] = f2b((acc[i][j][r] + bias) * scale);
            }
        }
      }
      __syncthreads();
      int h = ((n0 + nh * 64) & 1023) >> 6;
#pragma unroll
      for (int it = 0; it < 4; ++it) {
        int sl = it * 32 + (t >> 3);
        int ck = (t & 7) * 8;
        uint4 vv = *(uint4*)&Es[sl * 72 + ck];
        *(uint4*)&dst[(size_t)((bidx * 16 + h) * 2048 + s0 + sl) * 64 + ck] = vv;
      }
      __syncthreads();
    }
  }
}

// ---------------- flash attention ----------------
// Round-12: T15 pipeline (r10, measured 49.9us) + lacc MFMAs replaced by
// VALU sums of the BF16-ROUNDED P values (bit-identical math to the old
// P·1 MFMA, modulo f32 add order). Removes 4 of 36 MFMAs per kt. Epilogue:
// shfl_xor(16,32) folds fq groups; 128B per-wave LDS bounce (dead Pw buffer)
// redistributes the denominator to the C/D output indexing.
__global__ __launch_bounds__(256, 2) void attn_kernel(const unsigned short* __restrict__ qb,
                                                      const unsigned short* __restrict__ kb,
                                                      const unsigned short* __restrict__ vtb,
                                                      unsigned short* __restrict__ attn) {
  __shared__ unsigned short Ks[3 * 4096];
  __shared__ unsigned short Vs[3 * 4096];
  __shared__ unsigned short Ps[4 * 2048];
  const int t = threadIdx.x, lane = t & 63, w = t >> 6;
  const int fr = lane & 15, fq = lane >> 4;
  const int rid = blockIdx.y * 16 + blockIdx.x;
  const int bh = (rid & 7) + ((rid >> 7) << 3);
  const int q0 = ((rid >> 3) & 15) * 128;
  const int ksel = (fq ^ ((fr >> 1) & 3)) * 8;
  const unsigned short* qg = qb + (size_t)bh * 2048 * 64;
  const unsigned short* kg0 = kb + (size_t)bh * 2048 * 64;
  const unsigned short* vg0 = vtb + (size_t)bh * 64 * 2048;

  bf16x8 qf[2][2];
#pragma unroll
  for (int nb = 0; nb < 2; ++nb)
#pragma unroll
    for (int kk = 0; kk < 2; ++kk)
      qf[nb][kk] = *(const bf16x8*)(qg + (size_t)(q0 + w * 32 + nb * 16 + fr) * 64 + kk * 32 + fq * 8);

  f32x4 oacc[2][4] = {};
  float lsum0 = 0.f, lsum1 = 0.f;  // softmax denom partials for q = fr / 16+fr
  unsigned short* Pw = Ps + w * 2048;

  // staging helper: tile kt -> slot (slot == kt mod 3 by construction)
  auto STAGE = [&](int ktile, int slot) {
    const unsigned short* kg = kg0 + (size_t)ktile * 4096;
    const unsigned short* vg = vg0 + ktile * 64;
    int lb = slot * 4096;
#pragma unroll
    for (int rep = 0; rep < 2; ++rep) {
      int c = t + rep * 256;
      int kk = c >> 8, row = (c >> 2) & 63, cc = c & 3;
      int cs = cc ^ ((row >> 1) & 3);  // pre-swizzle global source chunk
      gld16(kg + row * 64 + kk * 32 + cs * 8, (void*)(Ks + lb + c * 8));
      gld16(vg + (size_t)row * 2048 + kk * 32 + cs * 8, (void*)(Vs + lb + c * 8));
    }
  };

  // ---- prologue ----
  STAGE(0, 0);
  __syncthreads();  // slot0 ready
  STAGE(1, 1);
  {  // QK^T(0) + SM(0)
    f32x4 sacc[4][2] = {};
#pragma unroll
    for (int kk = 0; kk < 2; ++kk) {
      bf16x8 kf[4];
#pragma unroll
      for (int m = 0; m < 4; ++m) kf[m] = *(const bf16x8*)&Ks[kk * 2048 + (m * 16 + fr) * 32 + ksel];
      __builtin_amdgcn_s_setprio(1);
#pragma unroll
      for (int m = 0; m < 4; ++m)
#pragma unroll
        for (int nb = 0; nb < 2; ++nb)
          sacc[m][nb] = __builtin_amdgcn_mfma_f32_16x16x32_bf16(kf[m], qf[nb][kk], sacc[m][nb], 0, 0, 0);
      __builtin_amdgcn_s_setprio(0);
    }
#pragma unroll
    for (int m = 0; m < 4; ++m)
#pragma unroll
      for (int nb = 0; nb < 2; ++nb) {
        int qw = nb * 16 + fr;
        int G = (m * 2 + (fq >> 1)) ^ (qw & 7);
        ushort4 pk;
        pk.x = f2b(__builtin_amdgcn_exp2f(sacc[m][nb][0]));
        pk.y = f2b(__builtin_amdgcn_exp2f(sacc[m][nb][1]));
        pk.z = f2b(__builtin_amdgcn_exp2f(sacc[m][nb][2]));
        pk.w = f2b(__builtin_amdgcn_exp2f(sacc[m][nb][3]));
        // sum the ROUNDED values (bit-consistent with the numerator's P)
        float r0 = __uint_as_float((unsigned)pk.x << 16);
        float r1 = __uint_as_float((unsigned)pk.y << 16);
        float r2 = __uint_as_float((unsigned)pk.z << 16);
        float r3 = __uint_as_float((unsigned)pk.w << 16);
        float s4 = (r0 + r1) + (r2 + r3);
        if (nb == 0) lsum0 += s4; else lsum1 += s4;
        *(uint2*)&Pw[qw * 64 + G * 8 + (fq & 1) * 4] = *(uint2*)&pk;
      }
  }
  __syncthreads();  // slot1 ready (drains STAGE(1))
  STAGE(2, 2);

  // ---- main pipeline: kt = 1..31 ----
  int prev = 0, cur = 1, nxt = 2;
  for (int kt = 1; kt < 32; ++kt) {
    const unsigned short* Kb = Ks + cur * 4096;
    const unsigned short* Vb = Vs + prev * 4096;
    f32x4 sacc[4][2] = {};
    __builtin_amdgcn_s_setprio(1);
    // QK^T(kt) from Kb
#pragma unroll
    for (int kk = 0; kk < 2; ++kk) {
      bf16x8 kf[4];
#pragma unroll
      for (int m = 0; m < 4; ++m) kf[m] = *(const bf16x8*)&Kb[kk * 2048 + (m * 16 + fr) * 32 + ksel];
#pragma unroll
      for (int m = 0; m < 4; ++m)
#pragma unroll
        for (int nb = 0; nb < 2; ++nb)
          sacc[m][nb] = __builtin_amdgcn_mfma_f32_16x16x32_bf16(kf[m], qf[nb][kk], sacc[m][nb], 0, 0, 0);
    }
    // PV(kt-1) from Pw + Vb (Pw reads precede this iteration's Pw writes;
    // per-wave DS ops are in-order, so no extra sync needed)
#pragma unroll
    for (int kk = 0; kk < 2; ++kk) {
      bf16x8 pf[2];
#pragma unroll
      for (int mb = 0; mb < 2; ++mb) {
        int qw = mb * 16 + fr;
        int G = (kk * 4 + fq) ^ (qw & 7);
        pf[mb] = *(const bf16x8*)&Pw[qw * 64 + G * 8];
      }
#pragma unroll
      for (int n = 0; n < 4; ++n) {
        bf16x8 vf = *(const bf16x8*)&Vb[kk * 2048 + (n * 16 + fr) * 32 + ksel];
#pragma unroll
        for (int mb = 0; mb < 2; ++mb)
          oacc[mb][n] = __builtin_amdgcn_mfma_f32_16x16x32_bf16(pf[mb], vf, oacc[mb][n], 0, 0, 0);
      }
    }
    __builtin_amdgcn_s_setprio(0);
    // SM(kt): sacc -> Pw (overwrites only after PV's reads in program order)
#pragma unroll
    for (int m = 0; m < 4; ++m)
#pragma unroll
      for (int nb = 0; nb < 2; ++nb) {
        int qw = nb * 16 + fr;
        int G = (m * 2 + (fq >> 1)) ^ (qw & 7);
        ushort4 pk;
        pk.x = f2b(__builtin_amdgcn_exp2f(sacc[m][nb][0]));
        pk.y = f2b(__builtin_amdgcn_exp2f(sacc[m][nb][1]));
        pk.z = f2b(__builtin_amdgcn_exp2f(sacc[m][nb][2]));
        pk.w = f2b(__builtin_amdgcn_exp2f(sacc[m][nb][3]));
        float r0 = __uint_as_float((unsigned)pk.x << 16);
        float r1 = __uint_as_float((unsigned)pk.y << 16);
        float r2 = __uint_as_float((unsigned)pk.z << 16);
        float r3 = __uint_as_float((unsigned)pk.w << 16);
        float s4 = (r0 + r1) + (r2 + r3);
        if (nb == 0) lsum0 += s4; else lsum1 += s4;
        *(uint2*)&Pw[qw * 64 + G * 8 + (fq & 1) * 4] = *(uint2*)&pk;
      }
    // one barrier per kt: all waves done reading slot `prev`; drains the
    // STAGE(kt+1) issued last iteration so slot `nxt` is ready for kt+1.
    __syncthreads();
    if (kt + 2 < 32) STAGE(kt + 2, prev);
    int tmp = prev; prev = cur; cur = nxt; nxt = tmp;
  }

  // ---- epilogue: PV(31) (V is in slot 31%3 == `prev` after final rotate) ----
  {
    const unsigned short* Vb = Vs + prev * 4096;
#pragma unroll
    for (int kk = 0; kk < 2; ++kk) {
      bf16x8 pf[2];
#pragma unroll
      for (int mb = 0; mb < 2; ++mb) {
        int qw = mb * 16 + fr;
        int G = (kk * 4 + fq) ^ (qw & 7);
        pf[mb] = *(const bf16x8*)&Pw[qw * 64 + G * 8];
      }
      __builtin_amdgcn_s_setprio(1);
#pragma unroll
      for (int n = 0; n < 4; ++n) {
        bf16x8 vf = *(const bf16x8*)&Vb[kk * 2048 + (n * 16 + fr) * 32 + ksel];
#pragma unroll
        for (int mb = 0; mb < 2; ++mb)
          oacc[mb][n] = __builtin_amdgcn_mfma_f32_16x16x32_bf16(pf[mb], vf, oacc[mb][n], 0, 0, 0);
      }
      __builtin_amdgcn_s_setprio(0);
    }
  }
  // fold fq groups: lanes fr, fr+16, fr+32, fr+48 hold partial sums for the
  // same q; after the two xors every lane has the full denominator.
  lsum0 += __shfl_xor(lsum0, 16);
  lsum0 += __shfl_xor(lsum0, 32);
  lsum1 += __shfl_xor(lsum1, 16);
  lsum1 += __shfl_xor(lsum1, 32);
  // redistribute q=nb*16+fr -> q=mb*16+fq*4+r via the dead Pw buffer
  float* Ldw = (float*)Pw;
  if (fq == 0) {
    Ldw[fr] = 1.f / lsum0;
    Ldw[16 + fr] = 1.f / lsum1;
  }
  __syncthreads();
  int bidx = bh >> 4, h = bh & 15;
#pragma unroll
  for (int mb = 0; mb < 2; ++mb)
#pragma unroll
    for (int r = 0; r < 4; ++r) {
      float inv = Ldw[mb * 16 + fq * 4 + r];
      int s = q0 + w * 32 + mb * 16 + fq * 4 + r;
      size_t base = (size_t)(bidx * 2048 + s) * 1024 + h * 64;
#pragma unroll
      for (int n = 0; n < 4; ++n) attn[base + n * 16 + fr] = f2b(oacc[mb][n][r] * inv);
    }
}

// ---------------- output projection (round-7 128x64 tiles, 2 blocks/CU — measured win) ----------------
__global__ __launch_bounds__(256) void gemm_out(const unsigned short* __restrict__ Ab,
                                                const unsigned short* __restrict__ Bt,
                                                const float* __restrict__ bo,
                                                float* __restrict__ out) {
  __shared__ unsigned short As[128 * 32];
  __shared__ unsigned short Bs[64 * 32];
  const int t = threadIdx.x;
  const int lane = t & 63, wave = t >> 6;
  const int m0 = blockIdx.x * 128, n0 = blockIdx.y * 64;
  const int wr = (wave >> 1) * 64, wc = (wave & 1) * 32;
  const int fr = lane & 15, fq = lane >> 4;
  f32x4 acc[4][2] = {};
  for (int kt = 0; kt < 32; ++kt) {
    const unsigned short* Ag = Ab + (size_t)m0 * 1024 + kt * 32;
    const unsigned short* Bg = Bt + (size_t)n0 * 1024 + kt * 32;
#pragma unroll
    for (int rep = 0; rep < 2; ++rep) {
      int c = t + rep * 256;
      int row = c >> 2, col = (c & 3) * 8;
      gld16(Ag + (size_t)row * 1024 + col, (void*)(As + c * 8));
    }
    {
      int c = t;
      int row = c >> 2, col = (c & 3) * 8;
      gld16(Bg + (size_t)row * 1024 + col, (void*)(Bs + c * 8));
    }
    __syncthreads();
    bf16x8 a[4], b[2];
#pragma unroll
    for (int i = 0; i < 4; ++i) a[i] = *(const bf16x8*)&As[(wr + i * 16 + fr) * 32 + fq * 8];
#pragma unroll
    for (int j = 0; j < 2; ++j) b[j] = *(const bf16x8*)&Bs[(wc + j * 16 + fr) * 32 + fq * 8];
#pragma unroll
    for (int i = 0; i < 4; ++i)
#pragma unroll
      for (int j = 0; j < 2; ++j)
        acc[i][j] = __builtin_amdgcn_mfma_f32_16x16x32_bf16(a[i], b[j], acc[i][j], 0, 0, 0);
    __syncthreads();
  }
#pragma unroll
  for (int j = 0; j < 2; ++j) {
    int gn = n0 + wc + j * 16 + fr;
    float bias = bo[gn];
#pragma unroll
    for (int i = 0; i < 4; ++i)
#pragma unroll
      for (int r = 0; r < 4; ++r) {
        int gm = m0 + wr + i * 16 + fq * 4 + r;
        out[(size_t)gm * 1024 + gn] = acc[i][j][r] + bias;
      }
  }
}

extern "C" void kernel_launch(void* const* d_in, const int* in_sizes, int n_in,
                              void* d_out, int out_size, void* d_ws, size_t ws_size,
                              hipStream_t stream) {
  const float* x = (const float*)d_in[0];
  const float* Wq = (const float*)d_in[1];
  const float* bq = (const float*)d_in[2];
  const float* Wk = (const float*)d_in[3];
  const float* bk = (const float*)d_in[4];
  const float* Wv = (const float*)d_in[5];
  const float* bv = (const float*)d_in[6];
  const float* Wo = (const float*)d_in[7];
  const float* bo = (const float*)d_in[8];
  float* out = (float*)d_out;

  unsigned short* ws = (unsigned short*)d_ws;
  const size_t MI = (size_t)1024 * 1024;
  unsigned short* xb = ws;
  unsigned short* wt = ws + 4 * MI;
  unsigned short* qb = wt + 4 * MI;
  unsigned short* kb = qb + 4 * MI;
  unsigned short* vtb = kb + 4 * MI;
  unsigned short* attn = xb;  // reuse xb after QKV gemm

  prep_kernel<<<5120, 256, 0, stream>>>(x, Wq, Wk, Wv, Wo, xb, wt);
  gemm_qkv<<<dim3(32, 24), 256, 0, stream>>>(xb, wt, bq, bk, bv, qb, kb, vtb);
  attn_kernel<<<dim3(16, 32), 256, 0, stream>>>(qb, kb, vtb, attn);
  gemm_out<<<dim3(32, 16), 256, 0, stream>>>(attn, wt + 3 * MI, bo, out);
}

// Round 13
// 199.589 us; speedup vs baseline: 1.0131x; 1.0131x over previous
//
#include <hip/hip_runtime.h>
#include <hip/hip_bf16.h>
#include <stdint.h>

// Problem constants: B=2, S=2048, D=1024, H=16, DH=64, M = B*S = 4096.
//
// FINAL CONSOLIDATION (round 13): best-measured component set.
//  - prep: r1 version (in the 196.8us best run)
//  - gemm_qkv: r1 BK=32 2-barrier loop (dbuf r2 and BK=64 r7 both regressed)
//  - attn: r10 T15 two-tile pipeline, 49.9us measured (lacc->VALU r12 regressed:
//    moved work from the 30%-busy MFMA pipe onto the serial VALU critical path)
//  - gemm_out: r7 128x64 tiles, 2 blocks/CU (r7 win)

typedef __attribute__((ext_vector_type(8))) short bf16x8;
typedef __attribute__((ext_vector_type(4))) float f32x4;

__device__ __forceinline__ void gld16(const void* g, void* l) {
  __builtin_amdgcn_global_load_lds((const __attribute__((address_space(1))) void*)g,
                                   (__attribute__((address_space(3))) void*)l, 16, 0, 0);
}

__device__ __forceinline__ unsigned short f2b(float f) {
  __hip_bfloat16 h = __float2bfloat16(f);
  return *reinterpret_cast<unsigned short*>(&h);
}

// ---------------- prep: x fp32->bf16 (blocks 0..4095) + W transpose (4096..5119) ----------------
__global__ __launch_bounds__(256) void prep_kernel(const float* __restrict__ x,
                                                   const float* __restrict__ Wq,
                                                   const float* __restrict__ Wk,
                                                   const float* __restrict__ Wv,
                                                   const float* __restrict__ Wo,
                                                   unsigned short* __restrict__ xb,
                                                   unsigned short* __restrict__ wt) {
  __shared__ unsigned short Ls[64 * 72];
  int bid = blockIdx.x;
  int t = threadIdx.x;
  if (bid < 4096) {
    int i = (bid * 256 + t) * 4;
    float4 v = *(const float4*)(x + i);
    ushort4 o = make_ushort4(f2b(v.x), f2b(v.y), f2b(v.z), f2b(v.w));
    *(ushort4*)(xb + i) = o;
    return;
  }
  int tid = bid - 4096;
  int z = tid >> 8, rem = tid & 255;
  int bx = rem & 15, by = rem >> 4;
  const float* src = (z == 0) ? Wq : (z == 1) ? Wk : (z == 2) ? Wv : Wo;
  unsigned short* dst = wt + (size_t)z * 1024 * 1024;
  int k0 = bx * 64, n0 = by * 64;
  int c4 = t & 15;
#pragma unroll
  for (int it = 0; it < 4; ++it) {
    int row = it * 16 + (t >> 4);
    float4 v = *(const float4*)(src + (k0 + row) * 1024 + n0 + c4 * 4);
    Ls[(c4 * 4 + 0) * 72 + row] = f2b(v.x);
    Ls[(c4 * 4 + 1) * 72 + row] = f2b(v.y);
    Ls[(c4 * 4 + 2) * 72 + row] = f2b(v.z);
    Ls[(c4 * 4 + 3) * 72 + row] = f2b(v.w);
  }
  __syncthreads();
  int nr = t >> 2, kc = (t & 3) * 16;
  *(uint4*)(dst + (size_t)(n0 + nr) * 1024 + k0 + kc) = *(uint4*)&Ls[nr * 72 + kc];
  *(uint4*)(dst + (size_t)(n0 + nr) * 1024 + k0 + kc + 8) = *(uint4*)&Ls[nr * 72 + kc + 8];
}

// ---------------- fused QKV GEMM (round-1 BK=32 structure — measured local optimum) ----------------
// Q is pre-scaled by 0.125*log2(e) so attention can use raw exp2.
__global__ __launch_bounds__(256) void gemm_qkv(const unsigned short* __restrict__ Ab,
                                                const unsigned short* __restrict__ Bt,
                                                const float* __restrict__ bq,
                                                const float* __restrict__ bk,
                                                const float* __restrict__ bv,
                                                unsigned short* __restrict__ qb,
                                                unsigned short* __restrict__ kb,
                                                unsigned short* __restrict__ vtb) {
  __shared__ unsigned short As[128 * 32];
  __shared__ unsigned short Bs[128 * 32];
  __shared__ unsigned short Es[128 * 72];  // also viewed as [64][136] for V (9216 >= 8704)
  const int t = threadIdx.x;
  const int lane = t & 63, wave = t >> 6;
  const int m0 = blockIdx.x * 128, n0 = blockIdx.y * 128;
  const int wr = (wave >> 1) * 64, wc = (wave & 1) * 64;
  const int fr = lane & 15, fq = lane >> 4;
  f32x4 acc[4][4] = {};
  for (int kt = 0; kt < 32; ++kt) {
    const unsigned short* Ag = Ab + (size_t)m0 * 1024 + kt * 32;
    const unsigned short* Bg = Bt + (size_t)n0 * 1024 + kt * 32;
#pragma unroll
    for (int rep = 0; rep < 2; ++rep) {
      int c = t + rep * 256;
      int row = c >> 2, col = (c & 3) * 8;
      gld16(Ag + (size_t)row * 1024 + col, (void*)(As + c * 8));
      gld16(Bg + (size_t)row * 1024 + col, (void*)(Bs + c * 8));
    }
    __syncthreads();
    bf16x8 a[4], b[4];
#pragma unroll
    for (int i = 0; i < 4; ++i) a[i] = *(const bf16x8*)&As[(wr + i * 16 + fr) * 32 + fq * 8];
#pragma unroll
    for (int j = 0; j < 4; ++j) b[j] = *(const bf16x8*)&Bs[(wc + j * 16 + fr) * 32 + fq * 8];
#pragma unroll
    for (int i = 0; i < 4; ++i)
#pragma unroll
      for (int j = 0; j < 4; ++j)
        acc[i][j] = __builtin_amdgcn_mfma_f32_16x16x32_bf16(a[i], b[j], acc[i][j], 0, 0, 0);
    __syncthreads();
  }
  const int which = n0 >> 10;  // 0=q, 1=k, 2=v (uniform per block)
  const int bidx = m0 >> 11, s0 = m0 & 2047;
  if (which == 2) {
    // V: Es as [dh_l][136] (s-contig rows), b64 LDS writes, 256-B coalesced global rows.
#pragma unroll
    for (int nh = 0; nh < 2; ++nh) {
      if ((wc >> 6) == nh) {
#pragma unroll
        for (int j = 0; j < 4; ++j) {
          int col = j * 16 + fr;  // dh_l 0..63
          float bias = bv[(n0 + nh * 64 + col) & 1023];
#pragma unroll
          for (int i = 0; i < 4; ++i) {
            int sl = wr + i * 16 + fq * 4;
            ushort4 pk;
            pk.x = f2b(acc[i][j][0] + bias);
            pk.y = f2b(acc[i][j][1] + bias);
            pk.z = f2b(acc[i][j][2] + bias);
            pk.w = f2b(acc[i][j][3] + bias);
            *(uint2*)&Es[col * 136 + sl] = *(uint2*)&pk;
          }
        }
      }
      __syncthreads();
      int h = ((n0 + nh * 64) & 1023) >> 6;
#pragma unroll
      for (int it = 0; it < 4; ++it) {
        int dh = it * 16 + (t >> 4);
        int ck = (t & 15) * 8;
        uint4 vv = *(uint4*)&Es[dh * 136 + ck];
        *(uint4*)&vtb[(size_t)((bidx * 16 + h) * 64 + dh) * 2048 + s0 + ck] = vv;
      }
      __syncthreads();
    }
  } else {
    unsigned short* dst = (which == 0) ? qb : kb;
    const float* bias_p = (which == 0) ? bq : bk;
    float scale = (which == 0) ? 0.1803368801111204f : 1.0f;
#pragma unroll
    for (int nh = 0; nh < 2; ++nh) {
      if ((wc >> 6) == nh) {
#pragma unroll
        for (int j = 0; j < 4; ++j) {
          int col = j * 16 + fr;
          float bias = bias_p[(n0 + nh * 64 + col) & 1023];
#pragma unroll
          for (int i = 0; i < 4; ++i)
#pragma unroll
            for (int r = 0; r < 4; ++r) {
              int sl = wr + i * 16 + fq * 4 + r;
              Es[sl * 72 + col] = f2b((acc[i][j][r] + bias) * scale);
            }
        }
      }
      __syncthreads();
      int h = ((n0 + nh * 64) & 1023) >> 6;
#pragma unroll
      for (int it = 0; it < 4; ++it) {
        int sl = it * 32 + (t >> 3);
        int ck = (t & 7) * 8;
        uint4 vv = *(uint4*)&Es[sl * 72 + ck];
        *(uint4*)&dst[(size_t)((bidx * 16 + h) * 2048 + s0 + sl) * 64 + ck] = vv;
      }
      __syncthreads();
    }
  }
}

// ---------------- flash attention (r10: T15 two-tile pipeline, 49.9us measured) ----------------
// Iteration kt runs {QK^T(kt) || PV(kt-1)} as ONE 36-MFMA cluster, then
// softmax(kt)->Pw, then one barrier, then STAGE(kt+2) into the freed slot.
// Triple-buffered K/V (slot == kt mod 3). Denominator via P·1 MFMA (lacc) --
// keeping it on the 30%-busy matrix pipe; the r12 VALU-sum variant regressed.
__global__ __launch_bounds__(256, 2) void attn_kernel(const unsigned short* __restrict__ qb,
                                                      const unsigned short* __restrict__ kb,
                                                      const unsigned short* __restrict__ vtb,
                                                      unsigned short* __restrict__ attn) {
  __shared__ unsigned short Ks[3 * 4096];
  __shared__ unsigned short Vs[3 * 4096];
  __shared__ unsigned short Ps[4 * 2048];
  const int t = threadIdx.x, lane = t & 63, w = t >> 6;
  const int fr = lane & 15, fq = lane >> 4;
  const int rid = blockIdx.y * 16 + blockIdx.x;
  const int bh = (rid & 7) + ((rid >> 7) << 3);
  const int q0 = ((rid >> 3) & 15) * 128;
  const int ksel = (fq ^ ((fr >> 1) & 3)) * 8;
  const unsigned short* qg = qb + (size_t)bh * 2048 * 64;
  const unsigned short* kg0 = kb + (size_t)bh * 2048 * 64;
  const unsigned short* vg0 = vtb + (size_t)bh * 64 * 2048;

  bf16x8 qf[2][2];
#pragma unroll
  for (int nb = 0; nb < 2; ++nb)
#pragma unroll
    for (int kk = 0; kk < 2; ++kk)
      qf[nb][kk] = *(const bf16x8*)(qg + (size_t)(q0 + w * 32 + nb * 16 + fr) * 64 + kk * 32 + fq * 8);

  bf16x8 ones;
#pragma unroll
  for (int i = 0; i < 8; ++i) ones[i] = (short)0x3F80;

  f32x4 oacc[2][4] = {};
  f32x4 lacc[2] = {};
  unsigned short* Pw = Ps + w * 2048;

  // staging helper: tile kt -> slot (slot == kt mod 3 by construction)
  auto STAGE = [&](int ktile, int slot) {
    const unsigned short* kg = kg0 + (size_t)ktile * 4096;
    const unsigned short* vg = vg0 + ktile * 64;
    int lb = slot * 4096;
#pragma unroll
    for (int rep = 0; rep < 2; ++rep) {
      int c = t + rep * 256;
      int kk = c >> 8, row = (c >> 2) & 63, cc = c & 3;
      int cs = cc ^ ((row >> 1) & 3);  // pre-swizzle global source chunk
      gld16(kg + row * 64 + kk * 32 + cs * 8, (void*)(Ks + lb + c * 8));
      gld16(vg + (size_t)row * 2048 + kk * 32 + cs * 8, (void*)(Vs + lb + c * 8));
    }
  };

  // ---- prologue ----
  STAGE(0, 0);
  __syncthreads();  // slot0 ready
  STAGE(1, 1);
  {  // QK^T(0) + SM(0)
    f32x4 sacc[4][2] = {};
#pragma unroll
    for (int kk = 0; kk < 2; ++kk) {
      bf16x8 kf[4];
#pragma unroll
      for (int m = 0; m < 4; ++m) kf[m] = *(const bf16x8*)&Ks[kk * 2048 + (m * 16 + fr) * 32 + ksel];
      __builtin_amdgcn_s_setprio(1);
#pragma unroll
      for (int m = 0; m < 4; ++m)
#pragma unroll
        for (int nb = 0; nb < 2; ++nb)
          sacc[m][nb] = __builtin_amdgcn_mfma_f32_16x16x32_bf16(kf[m], qf[nb][kk], sacc[m][nb], 0, 0, 0);
      __builtin_amdgcn_s_setprio(0);
    }
#pragma unroll
    for (int m = 0; m < 4; ++m)
#pragma unroll
      for (int nb = 0; nb < 2; ++nb) {
        int qw = nb * 16 + fr;
        int G = (m * 2 + (fq >> 1)) ^ (qw & 7);
        ushort4 pk;
        pk.x = f2b(__builtin_amdgcn_exp2f(sacc[m][nb][0]));
        pk.y = f2b(__builtin_amdgcn_exp2f(sacc[m][nb][1]));
        pk.z = f2b(__builtin_amdgcn_exp2f(sacc[m][nb][2]));
        pk.w = f2b(__builtin_amdgcn_exp2f(sacc[m][nb][3]));
        *(uint2*)&Pw[qw * 64 + G * 8 + (fq & 1) * 4] = *(uint2*)&pk;
      }
  }
  __syncthreads();  // slot1 ready (drains STAGE(1))
  STAGE(2, 2);

  // ---- main pipeline: kt = 1..31 ----
  int prev = 0, cur = 1, nxt = 2;
  for (int kt = 1; kt < 32; ++kt) {
    const unsigned short* Kb = Ks + cur * 4096;
    const unsigned short* Vb = Vs + prev * 4096;
    f32x4 sacc[4][2] = {};
    __builtin_amdgcn_s_setprio(1);
    // QK^T(kt) from Kb
#pragma unroll
    for (int kk = 0; kk < 2; ++kk) {
      bf16x8 kf[4];
#pragma unroll
      for (int m = 0; m < 4; ++m) kf[m] = *(const bf16x8*)&Kb[kk * 2048 + (m * 16 + fr) * 32 + ksel];
#pragma unroll
      for (int m = 0; m < 4; ++m)
#pragma unroll
        for (int nb = 0; nb < 2; ++nb)
          sacc[m][nb] = __builtin_amdgcn_mfma_f32_16x16x32_bf16(kf[m], qf[nb][kk], sacc[m][nb], 0, 0, 0);
    }
    // PV(kt-1) from Pw + Vb (Pw reads precede this iteration's Pw writes;
    // per-wave DS ops are in-order, so no extra sync needed)
#pragma unroll
    for (int kk = 0; kk < 2; ++kk) {
      bf16x8 pf[2];
#pragma unroll
      for (int mb = 0; mb < 2; ++mb) {
        int qw = mb * 16 + fr;
        int G = (kk * 4 + fq) ^ (qw & 7);
        pf[mb] = *(const bf16x8*)&Pw[qw * 64 + G * 8];
      }
#pragma unroll
      for (int n = 0; n < 4; ++n) {
        bf16x8 vf = *(const bf16x8*)&Vb[kk * 2048 + (n * 16 + fr) * 32 + ksel];
#pragma unroll
        for (int mb = 0; mb < 2; ++mb)
          oacc[mb][n] = __builtin_amdgcn_mfma_f32_16x16x32_bf16(pf[mb], vf, oacc[mb][n], 0, 0, 0);
      }
#pragma unroll
      for (int mb = 0; mb < 2; ++mb)
        lacc[mb] = __builtin_amdgcn_mfma_f32_16x16x32_bf16(pf[mb], ones, lacc[mb], 0, 0, 0);
    }
    __builtin_amdgcn_s_setprio(0);
    // SM(kt): sacc -> Pw (overwrites only after PV's reads in program order)
#pragma unroll
    for (int m = 0; m < 4; ++m)
#pragma unroll
      for (int nb = 0; nb < 2; ++nb) {
        int qw = nb * 16 + fr;
        int G = (m * 2 + (fq >> 1)) ^ (qw & 7);
        ushort4 pk;
        pk.x = f2b(__builtin_amdgcn_exp2f(sacc[m][nb][0]));
        pk.y = f2b(__builtin_amdgcn_exp2f(sacc[m][nb][1]));
        pk.z = f2b(__builtin_amdgcn_exp2f(sacc[m][nb][2]));
        pk.w = f2b(__builtin_amdgcn_exp2f(sacc[m][nb][3]));
        *(uint2*)&Pw[qw * 64 + G * 8 + (fq & 1) * 4] = *(uint2*)&pk;
      }
    // one barrier per kt: all waves done reading slot `prev`; drains the
    // STAGE(kt+1) issued last iteration so slot `nxt` is ready for kt+1.
    __syncthreads();
    if (kt + 2 < 32) STAGE(kt + 2, prev);
    int tmp = prev; prev = cur; cur = nxt; nxt = tmp;
  }

  // ---- epilogue: PV(31) (V is in slot 31%3 == `prev` after final rotate) ----
  {
    const unsigned short* Vb = Vs + prev * 4096;
#pragma unroll
    for (int kk = 0; kk < 2; ++kk) {
      bf16x8 pf[2];
#pragma unroll
      for (int mb = 0; mb < 2; ++mb) {
        int qw = mb * 16 + fr;
        int G = (kk * 4 + fq) ^ (qw & 7);
        pf[mb] = *(const bf16x8*)&Pw[qw * 64 + G * 8];
      }
      __builtin_amdgcn_s_setprio(1);
#pragma unroll
      for (int n = 0; n < 4; ++n) {
        bf16x8 vf = *(const bf16x8*)&Vb[kk * 2048 + (n * 16 + fr) * 32 + ksel];
#pragma unroll
        for (int mb = 0; mb < 2; ++mb)
          oacc[mb][n] = __builtin_amdgcn_mfma_f32_16x16x32_bf16(pf[mb], vf, oacc[mb][n], 0, 0, 0);
      }
#pragma unroll
      for (int mb = 0; mb < 2; ++mb)
        lacc[mb] = __builtin_amdgcn_mfma_f32_16x16x32_bf16(pf[mb], ones, lacc[mb], 0, 0, 0);
      __builtin_amdgcn_s_setprio(0);
    }
  }
  int bidx = bh >> 4, h = bh & 15;
#pragma unroll
  for (int mb = 0; mb < 2; ++mb)
#pragma unroll
    for (int r = 0; r < 4; ++r) {
      float inv = 1.f / lacc[mb][r];
      int s = q0 + w * 32 + mb * 16 + fq * 4 + r;
      size_t base = (size_t)(bidx * 2048 + s) * 1024 + h * 64;
#pragma unroll
      for (int n = 0; n < 4; ++n) attn[base + n * 16 + fr] = f2b(oacc[mb][n][r] * inv);
    }
}

// ---------------- output projection (round-7 128x64 tiles, 2 blocks/CU — measured win) ----------------
__global__ __launch_bounds__(256) void gemm_out(const unsigned short* __restrict__ Ab,
                                                const unsigned short* __restrict__ Bt,
                                                const float* __restrict__ bo,
                                                float* __restrict__ out) {
  __shared__ unsigned short As[128 * 32];
  __shared__ unsigned short Bs[64 * 32];
  const int t = threadIdx.x;
  const int lane = t & 63, wave = t >> 6;
  const int m0 = blockIdx.x * 128, n0 = blockIdx.y * 64;
  const int wr = (wave >> 1) * 64, wc = (wave & 1) * 32;
  const int fr = lane & 15, fq = lane >> 4;
  f32x4 acc[4][2] = {};
  for (int kt = 0; kt < 32; ++kt) {
    const unsigned short* Ag = Ab + (size_t)m0 * 1024 + kt * 32;
    const unsigned short* Bg = Bt + (size_t)n0 * 1024 + kt * 32;
#pragma unroll
    for (int rep = 0; rep < 2; ++rep) {
      int c = t + rep * 256;
      int row = c >> 2, col = (c & 3) * 8;
      gld16(Ag + (size_t)row * 1024 + col, (void*)(As + c * 8));
    }
    {
      int c = t;
      int row = c >> 2, col = (c & 3) * 8;
      gld16(Bg + (size_t)row * 1024 + col, (void*)(Bs + c * 8));
    }
    __syncthreads();
    bf16x8 a[4], b[2];
#pragma unroll
    for (int i = 0; i < 4; ++i) a[i] = *(const bf16x8*)&As[(wr + i * 16 + fr) * 32 + fq * 8];
#pragma unroll
    for (int j = 0; j < 2; ++j) b[j] = *(const bf16x8*)&Bs[(wc + j * 16 + fr) * 32 + fq * 8];
#pragma unroll
    for (int i = 0; i < 4; ++i)
#pragma unroll
      for (int j = 0; j < 2; ++j)
        acc[i][j] = __builtin_amdgcn_mfma_f32_16x16x32_bf16(a[i], b[j], acc[i][j], 0, 0, 0);
    __syncthreads();
  }
#pragma unroll
  for (int j = 0; j < 2; ++j) {
    int gn = n0 + wc + j * 16 + fr;
    float bias = bo[gn];
#pragma unroll
    for (int i = 0; i < 4; ++i)
#pragma unroll
      for (int r = 0; r < 4; ++r) {
        int gm = m0 + wr + i * 16 + fq * 4 + r;
        out[(size_t)gm * 1024 + gn] = acc[i][j][r] + bias;
      }
  }
}

extern "C" void kernel_launch(void* const* d_in, const int* in_sizes, int n_in,
                              void* d_out, int out_size, void* d_ws, size_t ws_size,
                              hipStream_t stream) {
  const float* x = (const float*)d_in[0];
  const float* Wq = (const float*)d_in[1];
  const float* bq = (const float*)d_in[2];
  const float* Wk = (const float*)d_in[3];
  const float* bk = (const float*)d_in[4];
  const float* Wv = (const float*)d_in[5];
  const float* bv = (const float*)d_in[6];
  const float* Wo = (const float*)d_in[7];
  const float* bo = (const float*)d_in[8];
  float* out = (float*)d_out;

  unsigned short* ws = (unsigned short*)d_ws;
  const size_t MI = (size_t)1024 * 1024;
  unsigned short* xb = ws;
  unsigned short* wt = ws + 4 * MI;
  unsigned short* qb = wt + 4 * MI;
  unsigned short* kb = qb + 4 * MI;
  unsigned short* vtb = kb + 4 * MI;
  unsigned short* attn = xb;  // reuse xb after QKV gemm

  prep_kernel<<<5120, 256, 0, stream>>>(x, Wq, Wk, Wv, Wo, xb, wt);
  gemm_qkv<<<dim3(32, 24), 256, 0, stream>>>(xb, wt, bq, bk, bv, qb, kb, vtb);
  attn_kernel<<<dim3(16, 32), 256, 0, stream>>>(qb, kb, vtb, attn);
  gemm_out<<<dim3(32, 16), 256, 0, stream>>>(attn, wt + 3 * MI, bo, out);
}

// Round 14
// 190.640 us; speedup vs baseline: 1.0607x; 1.0469x over previous
//
#include <hip/hip_runtime.h>
#include <hip/hip_bf16.h>
#include <stdint.h>

// Problem constants: B=2, S=2048, D=1024, H=16, DH=64, M = B*S = 4096.
//
// Round-14: gemm_qkv gets the r10-proven depth-2 pipeline (triple-buffered
// staging, STAGE issued AFTER the barrier, one barrier/kt) with the epilogue
// Es buffer ALIASED over the staging slots so LDS stays 48KB -> 3 blocks/CU
// (the occupancy r2's failed dbuf gave up). attn/prep/gemm_out = r13 verbatim.

typedef __attribute__((ext_vector_type(8))) short bf16x8;
typedef __attribute__((ext_vector_type(4))) float f32x4;

__device__ __forceinline__ void gld16(const void* g, void* l) {
  __builtin_amdgcn_global_load_lds((const __attribute__((address_space(1))) void*)g,
                                   (__attribute__((address_space(3))) void*)l, 16, 0, 0);
}

__device__ __forceinline__ unsigned short f2b(float f) {
  __hip_bfloat16 h = __float2bfloat16(f);
  return *reinterpret_cast<unsigned short*>(&h);
}

// ---------------- prep: x fp32->bf16 (blocks 0..4095) + W transpose (4096..5119) ----------------
__global__ __launch_bounds__(256) void prep_kernel(const float* __restrict__ x,
                                                   const float* __restrict__ Wq,
                                                   const float* __restrict__ Wk,
                                                   const float* __restrict__ Wv,
                                                   const float* __restrict__ Wo,
                                                   unsigned short* __restrict__ xb,
                                                   unsigned short* __restrict__ wt) {
  __shared__ unsigned short Ls[64 * 72];
  int bid = blockIdx.x;
  int t = threadIdx.x;
  if (bid < 4096) {
    int i = (bid * 256 + t) * 4;
    float4 v = *(const float4*)(x + i);
    ushort4 o = make_ushort4(f2b(v.x), f2b(v.y), f2b(v.z), f2b(v.w));
    *(ushort4*)(xb + i) = o;
    return;
  }
  int tid = bid - 4096;
  int z = tid >> 8, rem = tid & 255;
  int bx = rem & 15, by = rem >> 4;
  const float* src = (z == 0) ? Wq : (z == 1) ? Wk : (z == 2) ? Wv : Wo;
  unsigned short* dst = wt + (size_t)z * 1024 * 1024;
  int k0 = bx * 64, n0 = by * 64;
  int c4 = t & 15;
#pragma unroll
  for (int it = 0; it < 4; ++it) {
    int row = it * 16 + (t >> 4);
    float4 v = *(const float4*)(src + (k0 + row) * 1024 + n0 + c4 * 4);
    Ls[(c4 * 4 + 0) * 72 + row] = f2b(v.x);
    Ls[(c4 * 4 + 1) * 72 + row] = f2b(v.y);
    Ls[(c4 * 4 + 2) * 72 + row] = f2b(v.z);
    Ls[(c4 * 4 + 3) * 72 + row] = f2b(v.w);
  }
  __syncthreads();
  int nr = t >> 2, kc = (t & 3) * 16;
  *(uint4*)(dst + (size_t)(n0 + nr) * 1024 + k0 + kc) = *(uint4*)&Ls[nr * 72 + kc];
  *(uint4*)(dst + (size_t)(n0 + nr) * 1024 + k0 + kc + 8) = *(uint4*)&Ls[nr * 72 + kc + 8];
}

// ---------------- fused QKV GEMM ----------------
// Depth-2 prefetch pipeline (r10 attn pattern): compute(slot kt%3) -> barrier
// (drains STAGE(kt+1) issued last iteration; WAR-protects freed slot) ->
// STAGE(kt+2, freed). Loads get a full iteration+ to land instead of zero.
// Es aliases the staging memory (used strictly after the loop's last barrier)
// so LDS = 48KB and co-residency stays 3 blocks/CU.
// Q is pre-scaled by 0.125*log2(e) so attention can use raw exp2.
__global__ __launch_bounds__(256) void gemm_qkv(const unsigned short* __restrict__ Ab,
                                                const unsigned short* __restrict__ Bt,
                                                const float* __restrict__ bq,
                                                const float* __restrict__ bk,
                                                const float* __restrict__ bv,
                                                unsigned short* __restrict__ qb,
                                                unsigned short* __restrict__ kb,
                                                unsigned short* __restrict__ vtb) {
  __shared__ unsigned short smem[6 * 4096];  // 3 slots x (As 4096 + Bs 4096) shorts = 48KB
  unsigned short* Es = smem;                 // epilogue alias (needs 9216 shorts <= 24576)
  const int t = threadIdx.x;
  const int lane = t & 63, wave = t >> 6;
  const int m0 = blockIdx.x * 128, n0 = blockIdx.y * 128;
  const int wr = (wave >> 1) * 64, wc = (wave & 1) * 64;
  const int fr = lane & 15, fq = lane >> 4;
  f32x4 acc[4][4] = {};

  auto STAGE = [&](int ktile, int slot) {
    const unsigned short* Ag = Ab + (size_t)m0 * 1024 + ktile * 32;
    const unsigned short* Bg = Bt + (size_t)n0 * 1024 + ktile * 32;
    unsigned short* As = smem + slot * 8192;
    unsigned short* Bs = As + 4096;
#pragma unroll
    for (int rep = 0; rep < 2; ++rep) {
      int c = t + rep * 256;
      int row = c >> 2, col = (c & 3) * 8;
      gld16(Ag + (size_t)row * 1024 + col, (void*)(As + c * 8));
      gld16(Bg + (size_t)row * 1024 + col, (void*)(Bs + c * 8));
    }
  };

  // prologue
  STAGE(0, 0);
  __syncthreads();  // slot0 landed
  STAGE(1, 1);      // in flight; drained by the barrier at end of kt=0

  int cur = 0, nxt = 1, fre = 2;
  for (int kt = 0; kt < 32; ++kt) {
    const unsigned short* As = smem + cur * 8192;
    const unsigned short* Bs = As + 4096;
    bf16x8 a[4], b[4];
#pragma unroll
    for (int i = 0; i < 4; ++i) a[i] = *(const bf16x8*)&As[(wr + i * 16 + fr) * 32 + fq * 8];
#pragma unroll
    for (int j = 0; j < 4; ++j) b[j] = *(const bf16x8*)&Bs[(wc + j * 16 + fr) * 32 + fq * 8];
#pragma unroll
    for (int i = 0; i < 4; ++i)
#pragma unroll
      for (int j = 0; j < 4; ++j)
        acc[i][j] = __builtin_amdgcn_mfma_f32_16x16x32_bf16(a[i], b[j], acc[i][j], 0, 0, 0);
    // Barrier: (a) every wave drained its own STAGE(kt+1) gld16s (vmcnt(0)
    // precedes s_barrier), so slot `nxt` is fully landed for kt+1; (b) all
    // waves finished reading slot `fre` back in iteration kt-1 -> safe to
    // overwrite it with tile kt+2.
    __syncthreads();
    if (kt + 2 < 32) STAGE(kt + 2, fre);
    int tmp = fre; fre = cur; cur = nxt; nxt = tmp;
  }
  // From here on, all staging reads are complete (last barrier above), so Es
  // may alias the staging memory.
  const int which = n0 >> 10;  // 0=q, 1=k, 2=v (uniform per block)
  const int bidx = m0 >> 11, s0 = m0 & 2047;
  if (which == 2) {
    // V: Es as [dh_l][136] (s-contig rows), b64 LDS writes, 256-B coalesced global rows.
#pragma unroll
    for (int nh = 0; nh < 2; ++nh) {
      if ((wc >> 6) == nh) {
#pragma unroll
        for (int j = 0; j < 4; ++j) {
          int col = j * 16 + fr;  // dh_l 0..63
          float bias = bv[(n0 + nh * 64 + col) & 1023];
#pragma unroll
          for (int i = 0; i < 4; ++i) {
            int sl = wr + i * 16 + fq * 4;
            ushort4 pk;
            pk.x = f2b(acc[i][j][0] + bias);
            pk.y = f2b(acc[i][j][1] + bias);
            pk.z = f2b(acc[i][j][2] + bias);
            pk.w = f2b(acc[i][j][3] + bias);
            *(uint2*)&Es[col * 136 + sl] = *(uint2*)&pk;
          }
        }
      }
      __syncthreads();
      int h = ((n0 + nh * 64) & 1023) >> 6;
#pragma unroll
      for (int it = 0; it < 4; ++it) {
        int dh = it * 16 + (t >> 4);
        int ck = (t & 15) * 8;
        uint4 vv = *(uint4*)&Es[dh * 136 + ck];
        *(uint4*)&vtb[(size_t)((bidx * 16 + h) * 64 + dh) * 2048 + s0 + ck] = vv;
      }
      __syncthreads();
    }
  } else {
    unsigned short* dst = (which == 0) ? qb : kb;
    const float* bias_p = (which == 0) ? bq : bk;
    float scale = (which == 0) ? 0.1803368801111204f : 1.0f;
#pragma unroll
    for (int nh = 0; nh < 2; ++nh) {
      if ((wc >> 6) == nh) {
#pragma unroll
        for (int j = 0; j < 4; ++j) {
          int col = j * 16 + fr;
          float bias = bias_p[(n0 + nh * 64 + col) & 1023];
#pragma unroll
          for (int i = 0; i < 4; ++i)
#pragma unroll
            for (int r = 0; r < 4; ++r) {
              int sl = wr + i * 16 + fq * 4 + r;
              Es[sl * 72 + col] = f2b((acc[i][j][r] + bias) * scale);
            }
        }
      }
      __syncthreads();
      int h = ((n0 + nh * 64) & 1023) >> 6;
#pragma unroll
      for (int it = 0; it < 4; ++it) {
        int sl = it * 32 + (t >> 3);
        int ck = (t & 7) * 8;
        uint4 vv = *(uint4*)&Es[sl * 72 + ck];
        *(uint4*)&dst[(size_t)((bidx * 16 + h) * 2048 + s0 + sl) * 64 + ck] = vv;
      }
      __syncthreads();
    }
  }
}

// ---------------- flash attention (r10: T15 two-tile pipeline, 49.6-49.9us measured) ----------------
__global__ __launch_bounds__(256, 2) void attn_kernel(const unsigned short* __restrict__ qb,
                                                      const unsigned short* __restrict__ kb,
                                                      const unsigned short* __restrict__ vtb,
                                                      unsigned short* __restrict__ attn) {
  __shared__ unsigned short Ks[3 * 4096];
  __shared__ unsigned short Vs[3 * 4096];
  __shared__ unsigned short Ps[4 * 2048];
  const int t = threadIdx.x, lane = t & 63, w = t >> 6;
  const int fr = lane & 15, fq = lane >> 4;
  const int rid = blockIdx.y * 16 + blockIdx.x;
  const int bh = (rid & 7) + ((rid >> 7) << 3);
  const int q0 = ((rid >> 3) & 15) * 128;
  const int ksel = (fq ^ ((fr >> 1) & 3)) * 8;
  const unsigned short* qg = qb + (size_t)bh * 2048 * 64;
  const unsigned short* kg0 = kb + (size_t)bh * 2048 * 64;
  const unsigned short* vg0 = vtb + (size_t)bh * 64 * 2048;

  bf16x8 qf[2][2];
#pragma unroll
  for (int nb = 0; nb < 2; ++nb)
#pragma unroll
    for (int kk = 0; kk < 2; ++kk)
      qf[nb][kk] = *(const bf16x8*)(qg + (size_t)(q0 + w * 32 + nb * 16 + fr) * 64 + kk * 32 + fq * 8);

  bf16x8 ones;
#pragma unroll
  for (int i = 0; i < 8; ++i) ones[i] = (short)0x3F80;

  f32x4 oacc[2][4] = {};
  f32x4 lacc[2] = {};
  unsigned short* Pw = Ps + w * 2048;

  auto STAGE = [&](int ktile, int slot) {
    const unsigned short* kg = kg0 + (size_t)ktile * 4096;
    const unsigned short* vg = vg0 + ktile * 64;
    int lb = slot * 4096;
#pragma unroll
    for (int rep = 0; rep < 2; ++rep) {
      int c = t + rep * 256;
      int kk = c >> 8, row = (c >> 2) & 63, cc = c & 3;
      int cs = cc ^ ((row >> 1) & 3);  // pre-swizzle global source chunk
      gld16(kg + row * 64 + kk * 32 + cs * 8, (void*)(Ks + lb + c * 8));
      gld16(vg + (size_t)row * 2048 + kk * 32 + cs * 8, (void*)(Vs + lb + c * 8));
    }
  };

  // ---- prologue ----
  STAGE(0, 0);
  __syncthreads();  // slot0 ready
  STAGE(1, 1);
  {  // QK^T(0) + SM(0)
    f32x4 sacc[4][2] = {};
#pragma unroll
    for (int kk = 0; kk < 2; ++kk) {
      bf16x8 kf[4];
#pragma unroll
      for (int m = 0; m < 4; ++m) kf[m] = *(const bf16x8*)&Ks[kk * 2048 + (m * 16 + fr) * 32 + ksel];
      __builtin_amdgcn_s_setprio(1);
#pragma unroll
      for (int m = 0; m < 4; ++m)
#pragma unroll
        for (int nb = 0; nb < 2; ++nb)
          sacc[m][nb] = __builtin_amdgcn_mfma_f32_16x16x32_bf16(kf[m], qf[nb][kk], sacc[m][nb], 0, 0, 0);
      __builtin_amdgcn_s_setprio(0);
    }
#pragma unroll
    for (int m = 0; m < 4; ++m)
#pragma unroll
      for (int nb = 0; nb < 2; ++nb) {
        int qw = nb * 16 + fr;
        int G = (m * 2 + (fq >> 1)) ^ (qw & 7);
        ushort4 pk;
        pk.x = f2b(__builtin_amdgcn_exp2f(sacc[m][nb][0]));
        pk.y = f2b(__builtin_amdgcn_exp2f(sacc[m][nb][1]));
        pk.z = f2b(__builtin_amdgcn_exp2f(sacc[m][nb][2]));
        pk.w = f2b(__builtin_amdgcn_exp2f(sacc[m][nb][3]));
        *(uint2*)&Pw[qw * 64 + G * 8 + (fq & 1) * 4] = *(uint2*)&pk;
      }
  }
  __syncthreads();  // slot1 ready (drains STAGE(1))
  STAGE(2, 2);

  // ---- main pipeline: kt = 1..31 ----
  int prev = 0, cur = 1, nxt = 2;
  for (int kt = 1; kt < 32; ++kt) {
    const unsigned short* Kb = Ks + cur * 4096;
    const unsigned short* Vb = Vs + prev * 4096;
    f32x4 sacc[4][2] = {};
    __builtin_amdgcn_s_setprio(1);
    // QK^T(kt) from Kb
#pragma unroll
    for (int kk = 0; kk < 2; ++kk) {
      bf16x8 kf[4];
#pragma unroll
      for (int m = 0; m < 4; ++m) kf[m] = *(const bf16x8*)&Kb[kk * 2048 + (m * 16 + fr) * 32 + ksel];
#pragma unroll
      for (int m = 0; m < 4; ++m)
#pragma unroll
        for (int nb = 0; nb < 2; ++nb)
          sacc[m][nb] = __builtin_amdgcn_mfma_f32_16x16x32_bf16(kf[m], qf[nb][kk], sacc[m][nb], 0, 0, 0);
    }
    // PV(kt-1) from Pw + Vb (Pw reads precede this iteration's Pw writes;
    // per-wave DS ops are in-order, so no extra sync needed)
#pragma unroll
    for (int kk = 0; kk < 2; ++kk) {
      bf16x8 pf[2];
#pragma unroll
      for (int mb = 0; mb < 2; ++mb) {
        int qw = mb * 16 + fr;
        int G = (kk * 4 + fq) ^ (qw & 7);
        pf[mb] = *(const bf16x8*)&Pw[qw * 64 + G * 8];
      }
#pragma unroll
      for (int n = 0; n < 4; ++n) {
        bf16x8 vf = *(const bf16x8*)&Vb[kk * 2048 + (n * 16 + fr) * 32 + ksel];
#pragma unroll
        for (int mb = 0; mb < 2; ++mb)
          oacc[mb][n] = __builtin_amdgcn_mfma_f32_16x16x32_bf16(pf[mb], vf, oacc[mb][n], 0, 0, 0);
      }
#pragma unroll
      for (int mb = 0; mb < 2; ++mb)
        lacc[mb] = __builtin_amdgcn_mfma_f32_16x16x32_bf16(pf[mb], ones, lacc[mb], 0, 0, 0);
    }
    __builtin_amdgcn_s_setprio(0);
    // SM(kt): sacc -> Pw (overwrites only after PV's reads in program order)
#pragma unroll
    for (int m = 0; m < 4; ++m)
#pragma unroll
      for (int nb = 0; nb < 2; ++nb) {
        int qw = nb * 16 + fr;
        int G = (m * 2 + (fq >> 1)) ^ (qw & 7);
        ushort4 pk;
        pk.x = f2b(__builtin_amdgcn_exp2f(sacc[m][nb][0]));
        pk.y = f2b(__builtin_amdgcn_exp2f(sacc[m][nb][1]));
        pk.z = f2b(__builtin_amdgcn_exp2f(sacc[m][nb][2]));
        pk.w = f2b(__builtin_amdgcn_exp2f(sacc[m][nb][3]));
        *(uint2*)&Pw[qw * 64 + G * 8 + (fq & 1) * 4] = *(uint2*)&pk;
      }
    // one barrier per kt: all waves done reading slot `prev`; drains the
    // STAGE(kt+1) issued last iteration so slot `nxt` is ready for kt+1.
    __syncthreads();
    if (kt + 2 < 32) STAGE(kt + 2, prev);
    int tmp = prev; prev = cur; cur = nxt; nxt = tmp;
  }

  // ---- epilogue: PV(31) (V is in slot 31%3 == `prev` after final rotate) ----
  {
    const unsigned short* Vb = Vs + prev * 4096;
#pragma unroll
    for (int kk = 0; kk < 2; ++kk) {
      bf16x8 pf[2];
#pragma unroll
      for (int mb = 0; mb < 2; ++mb) {
        int qw = mb * 16 + fr;
        int G = (kk * 4 + fq) ^ (qw & 7);
        pf[mb] = *(const bf16x8*)&Pw[qw * 64 + G * 8];
      }
      __builtin_amdgcn_s_setprio(1);
#pragma unroll
      for (int n = 0; n < 4; ++n) {
        bf16x8 vf = *(const bf16x8*)&Vb[kk * 2048 + (n * 16 + fr) * 32 + ksel];
#pragma unroll
        for (int mb = 0; mb < 2; ++mb)
          oacc[mb][n] = __builtin_amdgcn_mfma_f32_16x16x32_bf16(pf[mb], vf, oacc[mb][n], 0, 0, 0);
      }
#pragma unroll
      for (int mb = 0; mb < 2; ++mb)
        lacc[mb] = __builtin_amdgcn_mfma_f32_16x16x32_bf16(pf[mb], ones, lacc[mb], 0, 0, 0);
      __builtin_amdgcn_s_setprio(0);
    }
  }
  int bidx = bh >> 4, h = bh & 15;
#pragma unroll
  for (int mb = 0; mb < 2; ++mb)
#pragma unroll
    for (int r = 0; r < 4; ++r) {
      float inv = 1.f / lacc[mb][r];
      int s = q0 + w * 32 + mb * 16 + fq * 4 + r;
      size_t base = (size_t)(bidx * 2048 + s) * 1024 + h * 64;
#pragma unroll
      for (int n = 0; n < 4; ++n) attn[base + n * 16 + fr] = f2b(oacc[mb][n][r] * inv);
    }
}

// ---------------- output projection (round-7 128x64 tiles, 2 blocks/CU — measured win) ----------------
__global__ __launch_bounds__(256) void gemm_out(const unsigned short* __restrict__ Ab,
                                                const unsigned short* __restrict__ Bt,
                                                const float* __restrict__ bo,
                                                float* __restrict__ out) {
  __shared__ unsigned short As[128 * 32];
  __shared__ unsigned short Bs[64 * 32];
  const int t = threadIdx.x;
  const int lane = t & 63, wave = t >> 6;
  const int m0 = blockIdx.x * 128, n0 = blockIdx.y * 64;
  const int wr = (wave >> 1) * 64, wc = (wave & 1) * 32;
  const int fr = lane & 15, fq = lane >> 4;
  f32x4 acc[4][2] = {};
  for (int kt = 0; kt < 32; ++kt) {
    const unsigned short* Ag = Ab + (size_t)m0 * 1024 + kt * 32;
    const unsigned short* Bg = Bt + (size_t)n0 * 1024 + kt * 32;
#pragma unroll
    for (int rep = 0; rep < 2; ++rep) {
      int c = t + rep * 256;
      int row = c >> 2, col = (c & 3) * 8;
      gld16(Ag + (size_t)row * 1024 + col, (void*)(As + c * 8));
    }
    {
      int c = t;
      int row = c >> 2, col = (c & 3) * 8;
      gld16(Bg + (size_t)row * 1024 + col, (void*)(Bs + c * 8));
    }
    __syncthreads();
    bf16x8 a[4], b[2];
#pragma unroll
    for (int i = 0; i < 4; ++i) a[i] = *(const bf16x8*)&As[(wr + i * 16 + fr) * 32 + fq * 8];
#pragma unroll
    for (int j = 0; j < 2; ++j) b[j] = *(const bf16x8*)&Bs[(wc + j * 16 + fr) * 32 + fq * 8];
#pragma unroll
    for (int i = 0; i < 4; ++i)
#pragma unroll
      for (int j = 0; j < 2; ++j)
        acc[i][j] = __builtin_amdgcn_mfma_f32_16x16x32_bf16(a[i], b[j], acc[i][j], 0, 0, 0);
    __syncthreads();
  }
#pragma unroll
  for (int j = 0; j < 2; ++j) {
    int gn = n0 + wc + j * 16 + fr;
    float bias = bo[gn];
#pragma unroll
    for (int i = 0; i < 4; ++i)
#pragma unroll
      for (int r = 0; r < 4; ++r) {
        int gm = m0 + wr + i * 16 + fq * 4 + r;
        out[(size_t)gm * 1024 + gn] = acc[i][j][r] + bias;
      }
  }
}

extern "C" void kernel_launch(void* const* d_in, const int* in_sizes, int n_in,
                              void* d_out, int out_size, void* d_ws, size_t ws_size,
                              hipStream_t stream) {
  const float* x = (const float*)d_in[0];
  const float* Wq = (const float*)d_in[1];
  const float* bq = (const float*)d_in[2];
  const float* Wk = (const float*)d_in[3];
  const float* bk = (const float*)d_in[4];
  const float* Wv = (const float*)d_in[5];
  const float* bv = (const float*)d_in[6];
  const float* Wo = (const float*)d_in[7];
  const float* bo = (const float*)d_in[8];
  float* out = (float*)d_out;

  unsigned short* ws = (unsigned short*)d_ws;
  const size_t MI = (size_t)1024 * 1024;
  unsigned short* xb = ws;
  unsigned short* wt = ws + 4 * MI;
  unsigned short* qb = wt + 4 * MI;
  unsigned short* kb = qb + 4 * MI;
  unsigned short* vtb = kb + 4 * MI;
  unsigned short* attn = xb;  // reuse xb after QKV gemm

  prep_kernel<<<5120, 256, 0, stream>>>(x, Wq, Wk, Wv, Wo, xb, wt);
  gemm_qkv<<<dim3(32, 24), 256, 0, stream>>>(xb, wt, bq, bk, bv, qb, kb, vtb);
  attn_kernel<<<dim3(16, 32), 256, 0, stream>>>(qb, kb, vtb, attn);
  gemm_out<<<dim3(32, 16), 256, 0, stream>>>(attn, wt + 3 * MI, bo, out);
}

// Round 15
// 189.725 us; speedup vs baseline: 1.0658x; 1.0048x over previous
//
#include <hip/hip_runtime.h>
#include <hip/hip_bf16.h>
#include <stdint.h>

// Problem constants: B=2, S=2048, D=1024, H=16, DH=64, M = B*S = 4096.
//
// Round-15: gemm_out gets the same depth-2 prefetch pipeline that took
// gemm_qkv from 49.6us to <49.4 (r14) and attn from 51.2 to 49.9 (r10):
// triple-buffered staging, STAGE issued AFTER the single per-kt barrier.
// prep / gemm_qkv / attn = r14 verbatim (190.6us total, best measured).

typedef __attribute__((ext_vector_type(8))) short bf16x8;
typedef __attribute__((ext_vector_type(4))) float f32x4;

__device__ __forceinline__ void gld16(const void* g, void* l) {
  __builtin_amdgcn_global_load_lds((const __attribute__((address_space(1))) void*)g,
                                   (__attribute__((address_space(3))) void*)l, 16, 0, 0);
}

__device__ __forceinline__ unsigned short f2b(float f) {
  __hip_bfloat16 h = __float2bfloat16(f);
  return *reinterpret_cast<unsigned short*>(&h);
}

// ---------------- prep: x fp32->bf16 (blocks 0..4095) + W transpose (4096..5119) ----------------
__global__ __launch_bounds__(256) void prep_kernel(const float* __restrict__ x,
                                                   const float* __restrict__ Wq,
                                                   const float* __restrict__ Wk,
                                                   const float* __restrict__ Wv,
                                                   const float* __restrict__ Wo,
                                                   unsigned short* __restrict__ xb,
                                                   unsigned short* __restrict__ wt) {
  __shared__ unsigned short Ls[64 * 72];
  int bid = blockIdx.x;
  int t = threadIdx.x;
  if (bid < 4096) {
    int i = (bid * 256 + t) * 4;
    float4 v = *(const float4*)(x + i);
    ushort4 o = make_ushort4(f2b(v.x), f2b(v.y), f2b(v.z), f2b(v.w));
    *(ushort4*)(xb + i) = o;
    return;
  }
  int tid = bid - 4096;
  int z = tid >> 8, rem = tid & 255;
  int bx = rem & 15, by = rem >> 4;
  const float* src = (z == 0) ? Wq : (z == 1) ? Wk : (z == 2) ? Wv : Wo;
  unsigned short* dst = wt + (size_t)z * 1024 * 1024;
  int k0 = bx * 64, n0 = by * 64;
  int c4 = t & 15;
#pragma unroll
  for (int it = 0; it < 4; ++it) {
    int row = it * 16 + (t >> 4);
    float4 v = *(const float4*)(src + (k0 + row) * 1024 + n0 + c4 * 4);
    Ls[(c4 * 4 + 0) * 72 + row] = f2b(v.x);
    Ls[(c4 * 4 + 1) * 72 + row] = f2b(v.y);
    Ls[(c4 * 4 + 2) * 72 + row] = f2b(v.z);
    Ls[(c4 * 4 + 3) * 72 + row] = f2b(v.w);
  }
  __syncthreads();
  int nr = t >> 2, kc = (t & 3) * 16;
  *(uint4*)(dst + (size_t)(n0 + nr) * 1024 + k0 + kc) = *(uint4*)&Ls[nr * 72 + kc];
  *(uint4*)(dst + (size_t)(n0 + nr) * 1024 + k0 + kc + 8) = *(uint4*)&Ls[nr * 72 + kc + 8];
}

// ---------------- fused QKV GEMM (r14: depth-2 pipeline, Es aliased, 3 blocks/CU) ----------------
// Q is pre-scaled by 0.125*log2(e) so attention can use raw exp2.
__global__ __launch_bounds__(256) void gemm_qkv(const unsigned short* __restrict__ Ab,
                                                const unsigned short* __restrict__ Bt,
                                                const float* __restrict__ bq,
                                                const float* __restrict__ bk,
                                                const float* __restrict__ bv,
                                                unsigned short* __restrict__ qb,
                                                unsigned short* __restrict__ kb,
                                                unsigned short* __restrict__ vtb) {
  __shared__ unsigned short smem[6 * 4096];  // 3 slots x (As 4096 + Bs 4096) shorts = 48KB
  unsigned short* Es = smem;                 // epilogue alias (needs 9216 shorts <= 24576)
  const int t = threadIdx.x;
  const int lane = t & 63, wave = t >> 6;
  const int m0 = blockIdx.x * 128, n0 = blockIdx.y * 128;
  const int wr = (wave >> 1) * 64, wc = (wave & 1) * 64;
  const int fr = lane & 15, fq = lane >> 4;
  f32x4 acc[4][4] = {};

  auto STAGE = [&](int ktile, int slot) {
    const unsigned short* Ag = Ab + (size_t)m0 * 1024 + ktile * 32;
    const unsigned short* Bg = Bt + (size_t)n0 * 1024 + ktile * 32;
    unsigned short* As = smem + slot * 8192;
    unsigned short* Bs = As + 4096;
#pragma unroll
    for (int rep = 0; rep < 2; ++rep) {
      int c = t + rep * 256;
      int row = c >> 2, col = (c & 3) * 8;
      gld16(Ag + (size_t)row * 1024 + col, (void*)(As + c * 8));
      gld16(Bg + (size_t)row * 1024 + col, (void*)(Bs + c * 8));
    }
  };

  // prologue
  STAGE(0, 0);
  __syncthreads();  // slot0 landed
  STAGE(1, 1);      // in flight; drained by the barrier at end of kt=0

  int cur = 0, nxt = 1, fre = 2;
  for (int kt = 0; kt < 32; ++kt) {
    const unsigned short* As = smem + cur * 8192;
    const unsigned short* Bs = As + 4096;
    bf16x8 a[4], b[4];
#pragma unroll
    for (int i = 0; i < 4; ++i) a[i] = *(const bf16x8*)&As[(wr + i * 16 + fr) * 32 + fq * 8];
#pragma unroll
    for (int j = 0; j < 4; ++j) b[j] = *(const bf16x8*)&Bs[(wc + j * 16 + fr) * 32 + fq * 8];
#pragma unroll
    for (int i = 0; i < 4; ++i)
#pragma unroll
      for (int j = 0; j < 4; ++j)
        acc[i][j] = __builtin_amdgcn_mfma_f32_16x16x32_bf16(a[i], b[j], acc[i][j], 0, 0, 0);
    // Barrier: drains STAGE(kt+1) (vmcnt(0) precedes s_barrier) so slot `nxt`
    // is landed for kt+1; WAR-protects slot `fre` (last read in kt-1).
    __syncthreads();
    if (kt + 2 < 32) STAGE(kt + 2, fre);
    int tmp = fre; fre = cur; cur = nxt; nxt = tmp;
  }
  // All staging reads complete (last barrier above) -> Es may alias staging.
  const int which = n0 >> 10;  // 0=q, 1=k, 2=v (uniform per block)
  const int bidx = m0 >> 11, s0 = m0 & 2047;
  if (which == 2) {
    // V: Es as [dh_l][136] (s-contig rows), b64 LDS writes, 256-B coalesced global rows.
#pragma unroll
    for (int nh = 0; nh < 2; ++nh) {
      if ((wc >> 6) == nh) {
#pragma unroll
        for (int j = 0; j < 4; ++j) {
          int col = j * 16 + fr;  // dh_l 0..63
          float bias = bv[(n0 + nh * 64 + col) & 1023];
#pragma unroll
          for (int i = 0; i < 4; ++i) {
            int sl = wr + i * 16 + fq * 4;
            ushort4 pk;
            pk.x = f2b(acc[i][j][0] + bias);
            pk.y = f2b(acc[i][j][1] + bias);
            pk.z = f2b(acc[i][j][2] + bias);
            pk.w = f2b(acc[i][j][3] + bias);
            *(uint2*)&Es[col * 136 + sl] = *(uint2*)&pk;
          }
        }
      }
      __syncthreads();
      int h = ((n0 + nh * 64) & 1023) >> 6;
#pragma unroll
      for (int it = 0; it < 4; ++it) {
        int dh = it * 16 + (t >> 4);
        int ck = (t & 15) * 8;
        uint4 vv = *(uint4*)&Es[dh * 136 + ck];
        *(uint4*)&vtb[(size_t)((bidx * 16 + h) * 64 + dh) * 2048 + s0 + ck] = vv;
      }
      __syncthreads();
    }
  } else {
    unsigned short* dst = (which == 0) ? qb : kb;
    const float* bias_p = (which == 0) ? bq : bk;
    float scale = (which == 0) ? 0.1803368801111204f : 1.0f;
#pragma unroll
    for (int nh = 0; nh < 2; ++nh) {
      if ((wc >> 6) == nh) {
#pragma unroll
        for (int j = 0; j < 4; ++j) {
          int col = j * 16 + fr;
          float bias = bias_p[(n0 + nh * 64 + col) & 1023];
#pragma unroll
          for (int i = 0; i < 4; ++i)
#pragma unroll
            for (int r = 0; r < 4; ++r) {
              int sl = wr + i * 16 + fq * 4 + r;
              Es[sl * 72 + col] = f2b((acc[i][j][r] + bias) * scale);
            }
        }
      }
      __syncthreads();
      int h = ((n0 + nh * 64) & 1023) >> 6;
#pragma unroll
      for (int it = 0; it < 4; ++it) {
        int sl = it * 32 + (t >> 3);
        int ck = (t & 7) * 8;
        uint4 vv = *(uint4*)&Es[sl * 72 + ck];
        *(uint4*)&dst[(size_t)((bidx * 16 + h) * 2048 + s0 + sl) * 64 + ck] = vv;
      }
      __syncthreads();
    }
  }
}

// ---------------- flash attention (r10: T15 two-tile pipeline, 49.5us measured) ----------------
__global__ __launch_bounds__(256, 2) void attn_kernel(const unsigned short* __restrict__ qb,
                                                      const unsigned short* __restrict__ kb,
                                                      const unsigned short* __restrict__ vtb,
                                                      unsigned short* __restrict__ attn) {
  __shared__ unsigned short Ks[3 * 4096];
  __shared__ unsigned short Vs[3 * 4096];
  __shared__ unsigned short Ps[4 * 2048];
  const int t = threadIdx.x, lane = t & 63, w = t >> 6;
  const int fr = lane & 15, fq = lane >> 4;
  const int rid = blockIdx.y * 16 + blockIdx.x;
  const int bh = (rid & 7) + ((rid >> 7) << 3);
  const int q0 = ((rid >> 3) & 15) * 128;
  const int ksel = (fq ^ ((fr >> 1) & 3)) * 8;
  const unsigned short* qg = qb + (size_t)bh * 2048 * 64;
  const unsigned short* kg0 = kb + (size_t)bh * 2048 * 64;
  const unsigned short* vg0 = vtb + (size_t)bh * 64 * 2048;

  bf16x8 qf[2][2];
#pragma unroll
  for (int nb = 0; nb < 2; ++nb)
#pragma unroll
    for (int kk = 0; kk < 2; ++kk)
      qf[nb][kk] = *(const bf16x8*)(qg + (size_t)(q0 + w * 32 + nb * 16 + fr) * 64 + kk * 32 + fq * 8);

  bf16x8 ones;
#pragma unroll
  for (int i = 0; i < 8; ++i) ones[i] = (short)0x3F80;

  f32x4 oacc[2][4] = {};
  f32x4 lacc[2] = {};
  unsigned short* Pw = Ps + w * 2048;

  auto STAGE = [&](int ktile, int slot) {
    const unsigned short* kg = kg0 + (size_t)ktile * 4096;
    const unsigned short* vg = vg0 + ktile * 64;
    int lb = slot * 4096;
#pragma unroll
    for (int rep = 0; rep < 2; ++rep) {
      int c = t + rep * 256;
      int kk = c >> 8, row = (c >> 2) & 63, cc = c & 3;
      int cs = cc ^ ((row >> 1) & 3);  // pre-swizzle global source chunk
      gld16(kg + row * 64 + kk * 32 + cs * 8, (void*)(Ks + lb + c * 8));
      gld16(vg + (size_t)row * 2048 + kk * 32 + cs * 8, (void*)(Vs + lb + c * 8));
    }
  };

  // ---- prologue ----
  STAGE(0, 0);
  __syncthreads();  // slot0 ready
  STAGE(1, 1);
  {  // QK^T(0) + SM(0)
    f32x4 sacc[4][2] = {};
#pragma unroll
    for (int kk = 0; kk < 2; ++kk) {
      bf16x8 kf[4];
#pragma unroll
      for (int m = 0; m < 4; ++m) kf[m] = *(const bf16x8*)&Ks[kk * 2048 + (m * 16 + fr) * 32 + ksel];
      __builtin_amdgcn_s_setprio(1);
#pragma unroll
      for (int m = 0; m < 4; ++m)
#pragma unroll
        for (int nb = 0; nb < 2; ++nb)
          sacc[m][nb] = __builtin_amdgcn_mfma_f32_16x16x32_bf16(kf[m], qf[nb][kk], sacc[m][nb], 0, 0, 0);
      __builtin_amdgcn_s_setprio(0);
    }
#pragma unroll
    for (int m = 0; m < 4; ++m)
#pragma unroll
      for (int nb = 0; nb < 2; ++nb) {
        int qw = nb * 16 + fr;
        int G = (m * 2 + (fq >> 1)) ^ (qw & 7);
        ushort4 pk;
        pk.x = f2b(__builtin_amdgcn_exp2f(sacc[m][nb][0]));
        pk.y = f2b(__builtin_amdgcn_exp2f(sacc[m][nb][1]));
        pk.z = f2b(__builtin_amdgcn_exp2f(sacc[m][nb][2]));
        pk.w = f2b(__builtin_amdgcn_exp2f(sacc[m][nb][3]));
        *(uint2*)&Pw[qw * 64 + G * 8 + (fq & 1) * 4] = *(uint2*)&pk;
      }
  }
  __syncthreads();  // slot1 ready (drains STAGE(1))
  STAGE(2, 2);

  // ---- main pipeline: kt = 1..31 ----
  int prev = 0, cur = 1, nxt = 2;
  for (int kt = 1; kt < 32; ++kt) {
    const unsigned short* Kb = Ks + cur * 4096;
    const unsigned short* Vb = Vs + prev * 4096;
    f32x4 sacc[4][2] = {};
    __builtin_amdgcn_s_setprio(1);
    // QK^T(kt) from Kb
#pragma unroll
    for (int kk = 0; kk < 2; ++kk) {
      bf16x8 kf[4];
#pragma unroll
      for (int m = 0; m < 4; ++m) kf[m] = *(const bf16x8*)&Kb[kk * 2048 + (m * 16 + fr) * 32 + ksel];
#pragma unroll
      for (int m = 0; m < 4; ++m)
#pragma unroll
        for (int nb = 0; nb < 2; ++nb)
          sacc[m][nb] = __builtin_amdgcn_mfma_f32_16x16x32_bf16(kf[m], qf[nb][kk], sacc[m][nb], 0, 0, 0);
    }
    // PV(kt-1) from Pw + Vb (Pw reads precede this iteration's Pw writes;
    // per-wave DS ops are in-order, so no extra sync needed)
#pragma unroll
    for (int kk = 0; kk < 2; ++kk) {
      bf16x8 pf[2];
#pragma unroll
      for (int mb = 0; mb < 2; ++mb) {
        int qw = mb * 16 + fr;
        int G = (kk * 4 + fq) ^ (qw & 7);
        pf[mb] = *(const bf16x8*)&Pw[qw * 64 + G * 8];
      }
#pragma unroll
      for (int n = 0; n < 4; ++n) {
        bf16x8 vf = *(const bf16x8*)&Vb[kk * 2048 + (n * 16 + fr) * 32 + ksel];
#pragma unroll
        for (int mb = 0; mb < 2; ++mb)
          oacc[mb][n] = __builtin_amdgcn_mfma_f32_16x16x32_bf16(pf[mb], vf, oacc[mb][n], 0, 0, 0);
      }
#pragma unroll
      for (int mb = 0; mb < 2; ++mb)
        lacc[mb] = __builtin_amdgcn_mfma_f32_16x16x32_bf16(pf[mb], ones, lacc[mb], 0, 0, 0);
    }
    __builtin_amdgcn_s_setprio(0);
    // SM(kt): sacc -> Pw (overwrites only after PV's reads in program order)
#pragma unroll
    for (int m = 0; m < 4; ++m)
#pragma unroll
      for (int nb = 0; nb < 2; ++nb) {
        int qw = nb * 16 + fr;
        int G = (m * 2 + (fq >> 1)) ^ (qw & 7);
        ushort4 pk;
        pk.x = f2b(__builtin_amdgcn_exp2f(sacc[m][nb][0]));
        pk.y = f2b(__builtin_amdgcn_exp2f(sacc[m][nb][1]));
        pk.z = f2b(__builtin_amdgcn_exp2f(sacc[m][nb][2]));
        pk.w = f2b(__builtin_amdgcn_exp2f(sacc[m][nb][3]));
        *(uint2*)&Pw[qw * 64 + G * 8 + (fq & 1) * 4] = *(uint2*)&pk;
      }
    // one barrier per kt: all waves done reading slot `prev`; drains the
    // STAGE(kt+1) issued last iteration so slot `nxt` is ready for kt+1.
    __syncthreads();
    if (kt + 2 < 32) STAGE(kt + 2, prev);
    int tmp = prev; prev = cur; cur = nxt; nxt = tmp;
  }

  // ---- epilogue: PV(31) (V is in slot 31%3 == `prev` after final rotate) ----
  {
    const unsigned short* Vb = Vs + prev * 4096;
#pragma unroll
    for (int kk = 0; kk < 2; ++kk) {
      bf16x8 pf[2];
#pragma unroll
      for (int mb = 0; mb < 2; ++mb) {
        int qw = mb * 16 + fr;
        int G = (kk * 4 + fq) ^ (qw & 7);
        pf[mb] = *(const bf16x8*)&Pw[qw * 64 + G * 8];
      }
      __builtin_amdgcn_s_setprio(1);
#pragma unroll
      for (int n = 0; n < 4; ++n) {
        bf16x8 vf = *(const bf16x8*)&Vb[kk * 2048 + (n * 16 + fr) * 32 + ksel];
#pragma unroll
        for (int mb = 0; mb < 2; ++mb)
          oacc[mb][n] = __builtin_amdgcn_mfma_f32_16x16x32_bf16(pf[mb], vf, oacc[mb][n], 0, 0, 0);
      }
#pragma unroll
      for (int mb = 0; mb < 2; ++mb)
        lacc[mb] = __builtin_amdgcn_mfma_f32_16x16x32_bf16(pf[mb], ones, lacc[mb], 0, 0, 0);
      __builtin_amdgcn_s_setprio(0);
    }
  }
  int bidx = bh >> 4, h = bh & 15;
#pragma unroll
  for (int mb = 0; mb < 2; ++mb)
#pragma unroll
    for (int r = 0; r < 4; ++r) {
      float inv = 1.f / lacc[mb][r];
      int s = q0 + w * 32 + mb * 16 + fq * 4 + r;
      size_t base = (size_t)(bidx * 2048 + s) * 1024 + h * 64;
#pragma unroll
      for (int n = 0; n < 4; ++n) attn[base + n * 16 + fr] = f2b(oacc[mb][n][r] * inv);
    }
}

// ---------------- output projection ----------------
// Round-15: depth-2 prefetch pipeline (same as r14 qkv). 3 slots x
// (As 8KB + Bs 4KB) = 36KB LDS; grid 512 -> 2 blocks/CU unchanged.
__global__ __launch_bounds__(256) void gemm_out(const unsigned short* __restrict__ Ab,
                                                const unsigned short* __restrict__ Bt,
                                                const float* __restrict__ bo,
                                                float* __restrict__ out) {
  __shared__ unsigned short smem[3 * 6144];  // 3 slots x (As 4096 + Bs 2048) shorts
  const int t = threadIdx.x;
  const int lane = t & 63, wave = t >> 6;
  const int m0 = blockIdx.x * 128, n0 = blockIdx.y * 64;
  const int wr = (wave >> 1) * 64, wc = (wave & 1) * 32;
  const int fr = lane & 15, fq = lane >> 4;
  f32x4 acc[4][2] = {};

  auto STAGE = [&](int ktile, int slot) {
    const unsigned short* Ag = Ab + (size_t)m0 * 1024 + ktile * 32;
    const unsigned short* Bg = Bt + (size_t)n0 * 1024 + ktile * 32;
    unsigned short* As = smem + slot * 6144;
    unsigned short* Bs = As + 4096;
#pragma unroll
    for (int rep = 0; rep < 2; ++rep) {
      int c = t + rep * 256;
      int row = c >> 2, col = (c & 3) * 8;
      gld16(Ag + (size_t)row * 1024 + col, (void*)(As + c * 8));
    }
    {
      int c = t;
      int row = c >> 2, col = (c & 3) * 8;
      gld16(Bg + (size_t)row * 1024 + col, (void*)(Bs + c * 8));
    }
  };

  // prologue
  STAGE(0, 0);
  __syncthreads();
  STAGE(1, 1);

  int cur = 0, nxt = 1, fre = 2;
  for (int kt = 0; kt < 32; ++kt) {
    const unsigned short* As = smem + cur * 6144;
    const unsigned short* Bs = As + 4096;
    bf16x8 a[4], b[2];
#pragma unroll
    for (int i = 0; i < 4; ++i) a[i] = *(const bf16x8*)&As[(wr + i * 16 + fr) * 32 + fq * 8];
#pragma unroll
    for (int j = 0; j < 2; ++j) b[j] = *(const bf16x8*)&Bs[(wc + j * 16 + fr) * 32 + fq * 8];
#pragma unroll
    for (int i = 0; i < 4; ++i)
#pragma unroll
      for (int j = 0; j < 2; ++j)
        acc[i][j] = __builtin_amdgcn_mfma_f32_16x16x32_bf16(a[i], b[j], acc[i][j], 0, 0, 0);
    __syncthreads();
    if (kt + 2 < 32) STAGE(kt + 2, fre);
    int tmp = fre; fre = cur; cur = nxt; nxt = tmp;
  }
#pragma unroll
  for (int j = 0; j < 2; ++j) {
    int gn = n0 + wc + j * 16 + fr;
    float bias = bo[gn];
#pragma unroll
    for (int i = 0; i < 4; ++i)
#pragma unroll
      for (int r = 0; r < 4; ++r) {
        int gm = m0 + wr + i * 16 + fq * 4 + r;
        out[(size_t)gm * 1024 + gn] = acc[i][j][r] + bias;
      }
  }
}

extern "C" void kernel_launch(void* const* d_in, const int* in_sizes, int n_in,
                              void* d_out, int out_size, void* d_ws, size_t ws_size,
                              hipStream_t stream) {
  const float* x = (const float*)d_in[0];
  const float* Wq = (const float*)d_in[1];
  const float* bq = (const float*)d_in[2];
  const float* Wk = (const float*)d_in[3];
  const float* bk = (const float*)d_in[4];
  const float* Wv = (const float*)d_in[5];
  const float* bv = (const float*)d_in[6];
  const float* Wo = (const float*)d_in[7];
  const float* bo = (const float*)d_in[8];
  float* out = (float*)d_out;

  unsigned short* ws = (unsigned short*)d_ws;
  const size_t MI = (size_t)1024 * 1024;
  unsigned short* xb = ws;
  unsigned short* wt = ws + 4 * MI;
  unsigned short* qb = wt + 4 * MI;
  unsigned short* kb = qb + 4 * MI;
  unsigned short* vtb = kb + 4 * MI;
  unsigned short* attn = xb;  // reuse xb after QKV gemm

  prep_kernel<<<5120, 256, 0, stream>>>(x, Wq, Wk, Wv, Wo, xb, wt);
  gemm_qkv<<<dim3(32, 24), 256, 0, stream>>>(xb, wt, bq, bk, bv, qb, kb, vtb);
  attn_kernel<<<dim3(16, 32), 256, 0, stream>>>(qb, kb, vtb, attn);
  gemm_out<<<dim3(32, 16), 256, 0, stream>>>(attn, wt + 3 * MI, bo, out);
}